// Round 1
// baseline (38.567 us; speedup 1.0000x reference)
//
#include <hip/hip_runtime.h>

// Problem constants (from the reference file)
constexpr int kC = 3;
constexpr int kH = 2048;
constexpr int kW = 2048;
constexpr int kNB = 256;      // N_BOXES
constexpr int kHeight = 32;   // HEIGHT

// One thread per output column c of one (box b, row r); covers all 3 channels.
// Replicates the reference's float32 arithmetic exactly (fp contract off).
__global__ __launch_bounds__(256) void extract_kernel(
    const float* __restrict__ img,
    const float* __restrict__ boxes,
    const float* __restrict__ scale,
    float* __restrict__ out,
    int max_w)
{
#pragma clang fp contract(off)
    const int c = blockIdx.x * blockDim.x + threadIdx.x;
    const int r = blockIdx.y;
    const int b = blockIdx.z;
    if (c >= max_w) return;

    const float s = scale[0];
    const float* bx = boxes + b * 8;      // boxes[b, 4, 2]
    const float p0x = bx[0] / s, p0y = bx[1] / s;
    const float p1x = bx[2] / s, p1y = bx[3] / s;
    const float p2x = bx[4] / s, p2y = bx[5] / s;
    const float p3x = bx[6] / s, p3y = bx[7] / s;

    // h_dists = |p2-p1|, w_dists = |p1-p0|
    const float hdx = p2x - p1x, hdy = p2y - p1y;
    const float h_dist = sqrtf(hdx * hdx + hdy * hdy);
    const float wdx = p1x - p0x, wdy = p1y - p0y;
    const float w_dist = sqrtf(wdx * wdx + wdy * wdy);
    // widths = (32 * w / clip(h,1e-6)).astype(int32)  -> trunc toward zero
    const int width = (int)(32.0f * w_dist / fmaxf(h_dist, 1e-6f));
    const float curr_w = (float)width;

    // widths_out[b] = widths//8*8 + 8, stored as float at the tail of d_out
    if (r == 0 && c == 0) {
        const int wo = width / 8 * 8 + 8;
        out[(size_t)kNB * kC * kHeight * max_w + b] = (float)wo;
    }

    const size_t ch_stride = (size_t)kHeight * max_w;
    // out[b][ch][r][c]
    const size_t obase = (((size_t)b * kC) * (size_t)kHeight + (size_t)r) * (size_t)max_w + (size_t)c;

    const float cf = (float)c;
    if (!(cf < curr_w)) {
        // mask==false -> grid=2.0 -> ix=3070 -> out of bounds -> 0
        out[obase] = 0.0f;
        out[obase + ch_stride] = 0.0f;
        out[obase + 2 * ch_stride] = 0.0f;
        return;
    }

    const float y = (float)r / 31.0f;                       // rows/(height-1)
    const float x = cf / fmaxf(curr_w - 1.0f, 1.0f);        // cols/clip(w-1,1)
    const float omx = 1.0f - x, omy = 1.0f - y;
    const float w00 = omx * omy;
    const float w10 = x * omy;
    const float w11 = x * y;
    const float w01 = omx * y;
    const float res_x = w00 * p0x + w10 * p1x + w11 * p2x + w01 * p3x;
    const float res_y = w00 * p0y + w10 * p1y + w11 * p2y + w01 * p3y;

    // grid_c = res_x/(W-1)*2-1 ; ix = round((grid_c+1)*(W-1)*0.5)  (half-to-even)
    const float grid_c = res_x / 2047.0f * 2.0f - 1.0f;
    const float grid_r = res_y / 2047.0f * 2.0f - 1.0f;
    const float fix = rintf((grid_c + 1.0f) * 2047.0f * 0.5f);
    const float fiy = rintf((grid_r + 1.0f) * 2047.0f * 0.5f);
    const bool inb = (fix >= 0.0f) && (fix <= 2047.0f) && (fiy >= 0.0f) && (fiy <= 2047.0f);
    const int ixc = (int)fminf(fmaxf(fix, 0.0f), 2047.0f);
    const int iyc = (int)fminf(fmaxf(fiy, 0.0f), 2047.0f);

    const size_t ipix = (size_t)iyc * kW + (size_t)ixc;
    const float s0 = img[ipix];
    const float s1 = img[(size_t)kH * kW + ipix];
    const float s2 = img[2 * (size_t)kH * kW + ipix];
    out[obase] = inb ? s0 : 0.0f;
    out[obase + ch_stride] = inb ? s1 : 0.0f;
    out[obase + 2 * ch_stride] = inb ? s2 : 0.0f;
}

extern "C" void kernel_launch(void* const* d_in, const int* in_sizes, int n_in,
                              void* d_out, int out_size, void* d_ws, size_t ws_size,
                              hipStream_t stream) {
    const float* img   = (const float*)d_in[0];
    const float* boxes = (const float*)d_in[1];
    const float* scale = (const float*)d_in[2];
    float* out = (float*)d_out;

    // out_size = NB*C*HEIGHT*max_w + NB  ->  max_w recoverable on host
    const int max_w = (out_size - kNB) / (kNB * kC * kHeight);

    dim3 grid((max_w + 255) / 256, kHeight, kNB);
    extract_kernel<<<grid, dim3(256, 1, 1), 0, stream>>>(img, boxes, scale, out, max_w);
}

// Round 3
// 23.756 us; speedup vs baseline: 1.6235x; 1.6235x over previous
//
#include <hip/hip_runtime.h>

// Problem constants (from the reference file)
constexpr int kC = 3;
constexpr int kH = 2048;
constexpr int kW = 2048;
constexpr int kNB = 256;      // N_BOXES
constexpr int kHeight = 32;   // HEIGHT

typedef float f32x4 __attribute__((ext_vector_type(4)));

// One thread per 4 output columns of one (box b, row r); covers all 3 channels.
// Replicates the reference's float32 arithmetic exactly (fp contract off).
__global__ __launch_bounds__(64) void extract_kernel(
    const float* __restrict__ img,
    const float* __restrict__ boxes,
    const float* __restrict__ scale,
    float* __restrict__ out,
    int max_w)
{
#pragma clang fp contract(off)
    const int r = blockIdx.y;
    const int b = blockIdx.z;
    const int c0 = (blockIdx.x * 64 + threadIdx.x) * 4;
    if (c0 >= max_w) return;

    const float s = scale[0];
    const float* bx = boxes + b * 8;      // boxes[b, 4, 2]
    const float p0x = bx[0] / s, p0y = bx[1] / s;
    const float p1x = bx[2] / s, p1y = bx[3] / s;
    const float p2x = bx[4] / s, p2y = bx[5] / s;
    const float p3x = bx[6] / s, p3y = bx[7] / s;

    // h_dists = |p2-p1|, w_dists = |p1-p0|
    const float hdx = p2x - p1x, hdy = p2y - p1y;
    const float h_dist = sqrtf(hdx * hdx + hdy * hdy);
    const float wdx = p1x - p0x, wdy = p1y - p0y;
    const float w_dist = sqrtf(wdx * wdx + wdy * wdy);
    // widths = (32 * w / clip(h,1e-6)).astype(int32)  -> trunc toward zero
    const int width = (int)(32.0f * w_dist / fmaxf(h_dist, 1e-6f));
    const float curr_w = (float)width;

    // widths_out[b] = widths//8*8 + 8, stored as float at the tail of d_out
    if (r == 0 && c0 == 0) {
        out[(size_t)kNB * kC * kHeight * max_w + b] = (float)(width / 8 * 8 + 8);
    }

    const size_t ch_stride = (size_t)kHeight * max_w;
    // out[b][ch][r][c0..c0+3]
    const size_t obase = (((size_t)b * kC) * (size_t)kHeight + (size_t)r) * (size_t)max_w + (size_t)c0;

    f32x4 o0 = {0.f, 0.f, 0.f, 0.f};
    f32x4 o1 = {0.f, 0.f, 0.f, 0.f};
    f32x4 o2 = {0.f, 0.f, 0.f, 0.f};

    if (c0 < width) {
        const float y = (float)r / 31.0f;                    // rows/(height-1)
        const float omy = 1.0f - y;
        const float xden = fmaxf(curr_w - 1.0f, 1.0f);       // clip(w-1,1)
#pragma unroll
        for (int j = 0; j < 4; ++j) {
            const float cf = (float)(c0 + j);
            if (cf < curr_w) {
                const float x = cf / xden;
                const float omx = 1.0f - x;
                const float w00 = omx * omy;
                const float w10 = x * omy;
                const float w11 = x * y;
                const float w01 = omx * y;
                const float res_x = w00 * p0x + w10 * p1x + w11 * p2x + w01 * p3x;
                const float res_y = w00 * p0y + w10 * p1y + w11 * p2y + w01 * p3y;

                const float grid_c = res_x / 2047.0f * 2.0f - 1.0f;
                const float grid_r = res_y / 2047.0f * 2.0f - 1.0f;
                const float fix = rintf((grid_c + 1.0f) * 2047.0f * 0.5f);
                const float fiy = rintf((grid_r + 1.0f) * 2047.0f * 0.5f);
                const bool inb = (fix >= 0.0f) && (fix <= 2047.0f) &&
                                 (fiy >= 0.0f) && (fiy <= 2047.0f);
                const int ixc = (int)fminf(fmaxf(fix, 0.0f), 2047.0f);
                const int iyc = (int)fminf(fmaxf(fiy, 0.0f), 2047.0f);

                const size_t ipix = (size_t)iyc * kW + (size_t)ixc;
                const float v0 = img[ipix];
                const float v1 = img[(size_t)kH * kW + ipix];
                const float v2 = img[2 * (size_t)kH * kW + ipix];
                o0[j] = inb ? v0 : 0.0f;
                o1[j] = inb ? v1 : 0.0f;
                o2[j] = inb ? v2 : 0.0f;
            }
        }
    }

    // 16B-aligned (max_w % 8 == 0, c0 % 4 == 0) streaming stores; output is
    // 64 MB > L2, keep it out of the cache the gather needs.
    __builtin_nontemporal_store(o0, (f32x4*)(out + obase));
    __builtin_nontemporal_store(o1, (f32x4*)(out + obase + ch_stride));
    __builtin_nontemporal_store(o2, (f32x4*)(out + obase + 2 * ch_stride));
}

extern "C" void kernel_launch(void* const* d_in, const int* in_sizes, int n_in,
                              void* d_out, int out_size, void* d_ws, size_t ws_size,
                              hipStream_t stream) {
    const float* img   = (const float*)d_in[0];
    const float* boxes = (const float*)d_in[1];
    const float* scale = (const float*)d_in[2];
    float* out = (float*)d_out;

    // out_size = NB*C*HEIGHT*max_w + NB  ->  max_w recoverable on host.
    // max_w is a multiple of 8 by construction (w//8*8+8).
    const int max_w = (out_size - kNB) / (kNB * kC * kHeight);
    const int quads = max_w / 4;

    dim3 grid((quads + 63) / 64, kHeight, kNB);
    extract_kernel<<<grid, dim3(64, 1, 1), 0, stream>>>(img, boxes, scale, out, max_w);
}